// Round 6
// baseline (771.752 us; speedup 1.0000x reference)
//
#include <hip/hip_runtime.h>
#include <cstdint>
#include <cstddef>

// Problem constants: P=2048, K=8, T=32, C=16384, F=128
#define PP 2048
#define KK 8
#define TT 32
#define FF 128
#define MB 8
#define NBLK (PP/MB)    // 256 blocks -> all 256 CUs, 1 block/CU
#define NTHR 1024       // 16 waves: 12 mm + 4 gate, 4 waves/SIMD
#define NSTEP (KK*TT)   // 256

typedef __attribute__((ext_vector_type(8))) short short8;  // 8 bf16 (4 VGPRs)
typedef __attribute__((ext_vector_type(4))) float f32x4;   // MFMA C/D frag

__device__ __forceinline__ uint32_t fbits(float x){ union{float f;uint32_t u;}c;c.f=x;return c.u; }
__device__ __forceinline__ uint32_t rne16(uint32_t u){
    return (u + 0x7fffu + ((u >> 16) & 1u)) >> 16;
}
__device__ __forceinline__ short bf_rne(float x){ return (short)rne16(fbits(x)); }
// HW packed f32->bf16 RNE: 1 instr (gfx950, no builtin)
__device__ __forceinline__ uint32_t cvtpk(float a, float b){
    uint32_t r;
    asm("v_cvt_pk_bf16_f32 %0, %1, %2" : "=v"(r) : "v"(a), "v"(b));
    return r;
}
__device__ __forceinline__ float sigm(float x){
    float t = __expf(-x);
    return __builtin_amdgcn_rcpf(1.f + t);
}
__device__ __forceinline__ float tanh_fast(float x){
    float e = __expf(-2.f * x);
    return __builtin_amdgcn_rcpf(1.f + e) * 2.f - 1.f;
}

#define MF(a,b,c) __builtin_amdgcn_mfma_f32_16x16x32_bf16(a,b,c,0,0,0)

// ROLE-SPLIT kernel: 8 paths x 256 steps, 16 waves (4/SIMD = real TLP).
//  - 12 mm-waves: wave w owns gate-output tiles {w, w+12} (24 tiles of 16
//    cols over 3F=384 outputs). Weights resident: 2 tiles x (wbi+wbh) =
//    64 VGPR. Per step: 8 h-MFMA (16 rows = 8 paths 2-dup, R3 map; C-in =
//    bias-folded x-preact accumulator for r/z tiles, bNh for n tiles),
//    then write pre-activations (f32) for its lanes' 2 owned paths to LDS.
//    Dense-x (2-step row pack + shfl exchange, R3-verified) runs in the
//    phase2 slots, split 4+4 MFMAs across the two phase2s of a step pair.
//  - 4 gate-waves (lane L: col f=L&127, paths 4*(L>>7)..+3): phase1 = stage
//    x(k+6) into the 8-ring + prefetch; phase2 = read 16 preacts, 4x
//    sigmoid/sigmoid/tanh/blend, update f32 h-masters, write bf16 h-frags
//    (sigma swizzle, R3 formulas). Final output from masters.
// Per SIMD: 3 mm + 1 gate wave -> gate VALU overlaps MFMA issue instead of
// serializing after it (R3's phases were disjoint: 34% mfma + 40% valu).
// MFMA issue unchanged vs R3 (2-dup preserved): 36/SIMD/step.
// 2 barriers/step; preact buffer (16.5KB) + h-frags (4KB) + x-ring (16KB).
__global__ __launch_bounds__(NTHR, 4) void gru_split(
    const float* __restrict__ h0,    // [P, F]
    const float* __restrict__ feat,  // [C, T, F]
    const float* __restrict__ w_ih,  // [3F, F]
    const float* __restrict__ w_hh,  // [3F, F]
    const float* __restrict__ b_ih,  // [3F]
    const float* __restrict__ b_hh,  // [3F]
    const int* __restrict__ idx,     // [P, K]
    float* __restrict__ out)         // [P, F]
{
    const int tid  = threadIdx.x;
    const int w    = tid >> 6;
    const int lane = tid & 63;
    const int q    = lane >> 4;
    const int nl   = lane & 15;
    const int p0   = blockIdx.x * MB;
    const bool isMM = (w < 12);

    __shared__ __align__(16) short hhi[2][4][32][8];  // h frags by parity (4KB)
    __shared__ __align__(16) short xr [8][4][32][8];  // x frag ring (16KB)
    __shared__ float pre[4][8][132];                  // planes r,z,hn,xn (16.5KB)
    __shared__ int cix[MB][KK];

    if (tid < MB * KK) cix[tid >> 3][tid & 7] = idx[(p0 + (tid >> 3)) * KK + (tid & 7)];

    // ---------------- mm-wave state ----------------
    short8 wi0[4], wh0[4], wi1[4], wh1[4];
    float biasA = 0.f, biasB = 0.f, biasB2 = 0.f;
    int gb = 0, oL = 0;
    const short* hr0 = nullptr;       // h-frag read base (+par*1024 +c*256)
    const short* xrb = nullptr;       // x-frag read base (+ring*1024 +c*256)
    float *pwA0 = nullptr, *pwA1 = nullptr, *pwB0 = nullptr, *pwB1 = nullptr;
    float *pwX0 = nullptr, *pwX1 = nullptr;
    float xEa0=0,xEa1=0,xOa0=0,xOa1=0,xEb0=0,xEb1=0,xOb0=0,xOb1=0;

    // ---------------- gate-wave state ----------------
    float hm0=0, hm1=0, hm2=0, hm3=0;
    float4 xp = {0,0,0,0};
    const float* prb = nullptr;
    short *hw0 = nullptr, *hw1 = nullptr, *hw2 = nullptr, *hw3 = nullptr;
    short* xw = nullptr;
    int path_s = 0, k0s = 0;

    if (isMM) {
        const int ta = w, tb = w + 12;
        const int ga = ta >> 3; const int cga = ta & 7;
        gb = tb >> 3;           const int cgb = tb & 7;
        const int fca = cga * 16 + nl, fcb = cgb * 16 + nl;
        const int rowa = ga * 128 + fca, rowb = gb * 128 + fcb;
#pragma unroll
        for (int c = 0; c < 4; ++c) {
            const float* a = w_ih + (size_t)rowa * FF + c * 32 + q * 8;
            const float* b = w_hh + (size_t)rowa * FF + c * 32 + q * 8;
            const float* d = w_ih + (size_t)rowb * FF + c * 32 + q * 8;
            const float* e = w_hh + (size_t)rowb * FF + c * 32 + q * 8;
            short8 t0, t1, t2, t3;
#pragma unroll
            for (int j = 0; j < 8; ++j) {
                t0[j] = bf_rne(a[j]); t1[j] = bf_rne(b[j]);
                t2[j] = bf_rne(d[j]); t3[j] = bf_rne(e[j]);
            }
            wi0[c] = t0; wh0[c] = t1; wi1[c] = t2; wh1[c] = t3;
        }
        biasA = b_ih[rowa] + b_hh[rowa];                 // ga in {0,1} always
        if (gb < 2) { biasB = b_ih[rowb] + b_hh[rowb]; }
        else        { biasB = b_ih[rowb]; biasB2 = b_hh[rowb]; }  // xn/hn biases

        // consumer maps (R3-verified): dup rows 8-15 = paths {2,3,0,1,6,7,4,5}
        const int pr = (nl < 8) ? nl : ((nl & 4) | ((nl & 3) ^ 2));
        const int hslot = (pr >> 2) + 2 * ((pr & 3) ^ q) + 8 * q;  // sigma
        hr0 = (const short*)hhi + hslot * 8;
        const int xslot = pr + 8 * q;                              // identity
        xrb = (const short*)xr + xslot * 8;
        oL  = nl >> 3;                                             // dense step-in-pair
        const int pb = 4 * (q & 1) + 2 * (q >> 1);   // C regs {0,1} = paths {pb,pb+1}
        pwA0 = &pre[ga][pb][fca];    pwA1 = &pre[ga][pb + 1][fca];
        const int gB = (gb < 2) ? gb : 2;
        pwB0 = &pre[gB][pb][fcb];    pwB1 = &pre[gB][pb + 1][fcb];
        pwX0 = &pre[3][pb][fcb];     pwX1 = &pre[3][pb + 1][fcb];
    } else {
        const int L = tid - 12 * 64;                  // 0..255
        const int f = L & 127, pg = L >> 7;
        // stager mapping (R3's, over 256 lanes)
        const int c_s = L >> 6, slot_s = (L >> 1) & 31, half = L & 1;
        path_s = slot_s & 7; const int qq_s = slot_s >> 3;
        k0s = c_s * 32 + qq_s * 8 + 4 * half;
        xw  = (short*)xr + c_s * 256 + slot_s * 8 + 4 * half;   // + ring*1024
        // gate mapping: 4 paths pg*4..+3 at col f
        const int cG = f >> 5, qqG = (f >> 3) & 3, jG = f & 7;
        prb = &pre[0][pg * 4][f];
        short* hbase = (short*)hhi + cG * 256 + jG;             // + par*1024
        const int sp0 = pg + 2 * (0 ^ qqG) + 8 * qqG;
        const int sp1 = pg + 2 * (1 ^ qqG) + 8 * qqG;
        const int sp2 = pg + 2 * (2 ^ qqG) + 8 * qqG;
        const int sp3 = pg + 2 * (3 ^ qqG) + 8 * qqG;
        hw0 = hbase + sp0 * 8; hw1 = hbase + sp1 * 8;
        hw2 = hbase + sp2 * 8; hw3 = hbase + sp3 * 8;
        // h0 masters + initial frags (parity 0)
        hm0 = h0[(size_t)(p0 + pg * 4 + 0) * FF + f];
        hm1 = h0[(size_t)(p0 + pg * 4 + 1) * FF + f];
        hm2 = h0[(size_t)(p0 + pg * 4 + 2) * FF + f];
        hm3 = h0[(size_t)(p0 + pg * 4 + 3) * FF + f];
        *hw0 = (short)cvtpk(hm0, hm0); *hw1 = (short)cvtpk(hm1, hm1);
        *hw2 = (short)cvtpk(hm2, hm2); *hw3 = (short)cvtpk(hm3, hm3);
    }
    __syncthreads();  // B0: cix + h0 frags ready

    // prologue: gate-waves stage steps 0..5 into rings 0..5, prefetch step 6
    if (!isMM) {
        const int ch = cix[path_s][0];
        const float* base = feat + (size_t)ch * (TT * FF) + k0s;
#pragma unroll
        for (int s = 0; s < 6; ++s) {
            const float4 v = *(const float4*)(base + s * FF);
            uint2 a = { cvtpk(v.x, v.y), cvtpk(v.z, v.w) };
            *(uint2*)(xw + s * 1024) = a;
        }
        xp = *(const float4*)(base + 6 * FF);
    }
    __syncthreads();  // B1: rings 0..5 staged

    // prologue dense: x-preacts for steps 0 (E) and 1 (O), both tiles
#define XCHG(d, E0, E1, O0, O1) {                    \
        const float s2_ = __shfl_xor(d[2], 32);      \
        const float s3_ = __shfl_xor(d[3], 32);      \
        const bool lo_ = (lane < 32);                \
        E0 = lo_ ? d[0] : s2_; E1 = lo_ ? d[1] : s3_;\
        O0 = lo_ ? s2_ : d[0]; O1 = lo_ ? s3_ : d[1]; }

    if (isMM) {
        const short* xb = xrb + (oL & 7) * 1024;
        const short8 x0 = *(const short8*)(xb);
        const short8 x1 = *(const short8*)(xb + 256);
        const short8 x2 = *(const short8*)(xb + 512);
        const short8 x3 = *(const short8*)(xb + 768);
        f32x4 dA = {biasA, biasA, biasA, biasA};
        dA = MF(x0, wi0[0], dA); dA = MF(x1, wi0[1], dA);
        dA = MF(x2, wi0[2], dA); dA = MF(x3, wi0[3], dA);
        f32x4 dB = {biasB, biasB, biasB, biasB};
        dB = MF(x0, wi1[0], dB); dB = MF(x1, wi1[1], dB);
        dB = MF(x2, wi1[2], dB); dB = MF(x3, wi1[3], dB);
        XCHG(dA, xEa0, xEa1, xOa0, xOa1)
        XCHG(dB, xEb0, xEb1, xOb0, xOb1)
    }

#define GATES(PARW) {                                                      \
        const float rp0 = prb[0],        rp1 = prb[132],                   \
                    rp2 = prb[264],      rp3 = prb[396];                   \
        const float zp0 = prb[1056],     zp1 = prb[1056+132],              \
                    zp2 = prb[1056+264], zp3 = prb[1056+396];              \
        const float hp0 = prb[2112],     hp1 = prb[2112+132],              \
                    hp2 = prb[2112+264], hp3 = prb[2112+396];              \
        const float xn0 = prb[3168],     xn1 = prb[3168+132],              \
                    xn2 = prb[3168+264], xn3 = prb[3168+396];              \
        float n_;                                                          \
        n_ = tanh_fast(xn0 + sigm(rp0) * hp0);                            \
        hm0 = n_ + sigm(zp0) * (hm0 - n_);                                \
        n_ = tanh_fast(xn1 + sigm(rp1) * hp1);                            \
        hm1 = n_ + sigm(zp1) * (hm1 - n_);                                \
        n_ = tanh_fast(xn2 + sigm(rp2) * hp2);                            \
        hm2 = n_ + sigm(zp2) * (hm2 - n_);                                \
        n_ = tanh_fast(xn3 + sigm(rp3) * hp3);                            \
        hm3 = n_ + sigm(zp3) * (hm3 - n_);                                \
        *(hw0 + (PARW)*1024) = (short)cvtpk(hm0, hm0);                    \
        *(hw1 + (PARW)*1024) = (short)cvtpk(hm1, hm1);                    \
        *(hw2 + (PARW)*1024) = (short)cvtpk(hm2, hm2);                    \
        *(hw3 + (PARW)*1024) = (short)cvtpk(hm3, hm3);                    \
    }

#define HMFMA(PAR, XB0, XB1)  {                                            \
        const short* hb = hr0 + (PAR) * 1024;                              \
        const short8 h0f = *(const short8*)(hb);                           \
        const short8 h1f = *(const short8*)(hb + 256);                     \
        const short8 h2f = *(const short8*)(hb + 512);                     \
        const short8 h3f = *(const short8*)(hb + 768);                     \
        f32x4 ca = {XB0##a0, XB0##a1, XB0##a0, XB0##a1};                   \
        ca = MF(h0f, wh0[0], ca); ca = MF(h1f, wh0[1], ca);                \
        ca = MF(h2f, wh0[2], ca); ca = MF(h3f, wh0[3], ca);                \
        f32x4 cb;                                                          \
        if (gb == 2) cb = (f32x4){biasB2, biasB2, biasB2, biasB2};         \
        else         cb = (f32x4){XB0##b0, XB0##b1, XB0##b0, XB0##b1};     \
        cb = MF(h0f, wh1[0], cb); cb = MF(h1f, wh1[1], cb);                \
        cb = MF(h2f, wh1[2], cb); cb = MF(h3f, wh1[3], cb);                \
        *pwA0 = ca[0]; *pwA1 = ca[1];                                      \
        *pwB0 = cb[0]; *pwB1 = cb[1];                                      \
        if (gb == 2) { *pwX0 = XB0##b0; *pwX1 = XB0##b1; }                 \
    }

    for (int m2 = 0; m2 < NSTEP / 2; ++m2) {
        const int k = 2 * m2;
        f32x4 dA, dB;
        const bool dodense = (m2 < NSTEP / 2 - 1);

        // ===== even step k: phase 1 (par 0)
        if (isMM) {
            HMFMA(0, xE, unused)
        } else {
            const int s6 = k + 6;
            if (s6 < NSTEP) {
                uint2 a = { cvtpk(xp.x, xp.y), cvtpk(xp.z, xp.w) };
                *(uint2*)(xw + (s6 & 7) * 1024) = a;
            }
            const int s7 = k + 7;
            if (s7 < NSTEP) {
                const int ch = cix[path_s][s7 >> 5];
                xp = *(const float4*)(feat + (size_t)ch * (TT * FF) + (s7 & 31) * FF + k0s);
            }
        }
        __syncthreads();

        // ===== even phase 2: gates(k) || dense-lo (steps k+2,k+3 chunks 0,1)
        if (isMM) {
            if (dodense) {
                const short* xb = xrb + (((k + 2 + oL) & 7)) * 1024;
                const short8 x0 = *(const short8*)(xb);
                const short8 x1 = *(const short8*)(xb + 256);
                dA = (f32x4){biasA, biasA, biasA, biasA};
                dA = MF(x0, wi0[0], dA); dA = MF(x1, wi0[1], dA);
                dB = (f32x4){biasB, biasB, biasB, biasB};
                dB = MF(x0, wi1[0], dB); dB = MF(x1, wi1[1], dB);
            }
        } else {
            GATES(1)
        }
        __syncthreads();

        // ===== odd step k+1: phase 1 (par 1)
        if (isMM) {
            HMFMA(1, xO, unused)
        } else {
            const int s6 = k + 7;
            if (s6 < NSTEP) {
                uint2 a = { cvtpk(xp.x, xp.y), cvtpk(xp.z, xp.w) };
                *(uint2*)(xw + (s6 & 7) * 1024) = a;
            }
            const int s7 = k + 8;
            if (s7 < NSTEP) {
                const int ch = cix[path_s][s7 >> 5];
                xp = *(const float4*)(feat + (size_t)ch * (TT * FF) + (s7 & 31) * FF + k0s);
            }
        }
        __syncthreads();

        // ===== odd phase 2: gates(k+1) || dense-hi (chunks 2,3) + exchange
        if (isMM) {
            if (dodense) {
                const short* xb = xrb + (((k + 2 + oL) & 7)) * 1024;
                const short8 x2 = *(const short8*)(xb + 512);
                const short8 x3 = *(const short8*)(xb + 768);
                dA = MF(x2, wi0[2], dA); dA = MF(x3, wi0[3], dA);
                dB = MF(x2, wi1[2], dB); dB = MF(x3, wi1[3], dB);
                XCHG(dA, xEa0, xEa1, xOa0, xOa1)
                XCHG(dB, xEb0, xEb1, xOb0, xOb1)
            }
        } else {
            GATES(0)
        }
        __syncthreads();
    }

    // epilogue: final h from gate-wave masters
    if (!isMM) {
        const int L = tid - 12 * 64;
        const int f = L & 127, pg = L >> 7;
        out[(size_t)(p0 + pg * 4 + 0) * FF + f] = hm0;
        out[(size_t)(p0 + pg * 4 + 1) * FF + f] = hm1;
        out[(size_t)(p0 + pg * 4 + 2) * FF + f] = hm2;
        out[(size_t)(p0 + pg * 4 + 3) * FF + f] = hm3;
    }
}

extern "C" void kernel_launch(void* const* d_in, const int* in_sizes, int n_in,
                              void* d_out, int out_size, void* d_ws, size_t ws_size,
                              hipStream_t stream) {
    const float* h0   = (const float*)d_in[0];
    const float* feat = (const float*)d_in[1];
    const float* wih  = (const float*)d_in[2];
    const float* whh  = (const float*)d_in[3];
    const float* bih  = (const float*)d_in[4];
    const float* bhh  = (const float*)d_in[5];
    const int*   idx  = (const int*)d_in[6];
    float*       out  = (float*)d_out;

    gru_split<<<dim3(NBLK), dim3(NTHR), 0, stream>>>(
        h0, feat, wih, whh, bih, bhh, idx, out);
}